// Round 9
// baseline (229.158 us; speedup 1.0000x reference)
//
#include <hip/hip_runtime.h>
#include <hip/hip_bf16.h>

#define BATCH   65536
#define FEAT    128
#define KDIM    256

typedef __attribute__((ext_vector_type(8))) short bf16x8;
typedef __attribute__((ext_vector_type(4))) float f32x4;

__device__ __forceinline__ short f2bf(float f) {
    return __builtin_bit_cast(short, __float2bfloat16(f));
}

__device__ __forceinline__ bf16x8 cvt8(f32x4 lo, f32x4 hi) {
    bf16x8 r;
    r[0] = f2bf(lo[0]); r[1] = f2bf(lo[1]); r[2] = f2bf(lo[2]); r[3] = f2bf(lo[3]);
    r[4] = f2bf(hi[0]); r[5] = f2bf(hi[1]); r[6] = f2bf(hi[2]); r[7] = f2bf(hi[3]);
    return r;
}

__device__ __forceinline__ float sigmoidf_(float x) {
    return 1.0f / (1.0f + __expf(-x));
}
__device__ __forceinline__ float tanhf_(float x) {
    float xc = fminf(fmaxf(x, -15.0f), 15.0f);
    float e = __expf(-2.0f * xc);
    return (1.0f - e) / (1.0f + e);
}

// ---- prep: convert W (fp32, [gate][128][256]) into bf16 MFMA B-fragments ----
// frag index f = ((cg*4 + g)*8 + ks)*64 + lane ; lane=(lr,lk) holds
// W_g[cg*16+lr][ks*32 + lk*8 .. +8]. 16384 frags x 16 B = 256 KB in d_ws.
__global__ __launch_bounds__(256)
void prep_w(const float* __restrict__ Wf, const float* __restrict__ Wi,
            const float* __restrict__ Wo, const float* __restrict__ Wc,
            bf16x8* __restrict__ wsf)
{
    const int f    = blockIdx.x * 256 + threadIdx.x;   // 0..16383
    const int lane = f & 63;
    const int ks   = (f >> 6) & 7;
    const int g    = (f >> 9) & 3;
    const int cg   = f >> 11;
    const int lr   = lane & 15, lk = lane >> 4;
    const float* W = (g == 0) ? Wf : (g == 1) ? Wi : (g == 2) ? Wo : Wc;
    const float* s = W + (size_t)(cg * 16 + lr) * KDIM + ks * 32 + lk * 8;
    wsf[f] = cvt8(*(const f32x4*)s, *(const f32x4*)(s + 4));
}

// ---- main: barrier-free streaming LSTM ----
// Block = 512 thr = 8 waves; wave wid owns column-group cg=wid -> all 8 waves
// read the SAME 32 A-rows (L1-shared, A fetched from HBM once). Wave tile:
// 32 rows x 16 cols x 4 gates, full K=256 pipelined in quarters; W-fragments
// re-read from d_ws (L2-resident, anti-CSE asm blocks the 128-reg hoist).
// Zero barriers, zero LDS, lane-local LSTM epilogue (v1-proven C/D layout).
__global__ __launch_bounds__(512, 2)
void lstm_v6(const float* __restrict__ inp, const float* __restrict__ hid,
             const float* __restrict__ cel,
             const float* __restrict__ bfp, const float* __restrict__ bip,
             const float* __restrict__ bop, const float* __restrict__ bcp,
             const bf16x8* __restrict__ wsf, float* __restrict__ out)
{
    const int tid  = threadIdx.x;
    const int lane = tid & 63;
    const int wid  = tid >> 6;          // 0..7 = column group cg
    const int bid  = blockIdx.x;        // 0..511
    const int lr   = lane & 15;
    const int lk   = lane >> 4;
    const int j    = wid * 16 + lr;     // hidden-unit column

    const bf16x8* wfb0 = wsf + wid * 2048;   // this cg's frags: [(g*8+ks)*64+lane]
    const float bsf = bfp[j], bsi = bip[j], bso = bop[j], bsc = bcp[j];

    float* outH = out;
    float* outC = out + (size_t)BATCH * FEAT;

    f32x4 slo[4], shi[4];   // staging for one K-quarter: [mb*2+c]

    // prologue: stage (it=0, kq=0) = inp cols 0..63
    {
        const float* a = inp + (size_t)(bid * 32 + lr) * FEAT + lk * 8;
        #pragma unroll
        for (int mb = 0; mb < 2; ++mb)
            #pragma unroll
            for (int c = 0; c < 2; ++c) {
                slo[mb * 2 + c] = *(const f32x4*)(a + mb * 16 * FEAT + c * 32);
                shi[mb * 2 + c] = *(const f32x4*)(a + mb * 16 * FEAT + c * 32 + 4);
            }
    }

    for (int it = 0; it < 4; ++it) {
        const int R0 = (bid + it * 512) * 32;

        // anti-CSE: force W-frag reloads each iteration (L2 hits) instead of
        // hoisting 128 VGPRs of W out of the loop (round-1 spill pathology).
        unsigned zoff = 0;
        asm volatile("" : "+s"(zoff));
        const bf16x8* wfb = wfb0 + zoff;

        // cel prefetch for this iter (latency covered by 4 MFMA quarters)
        float cv[8];
        #pragma unroll
        for (int mb = 0; mb < 2; ++mb)
            #pragma unroll
            for (int t = 0; t < 4; ++t)
                cv[mb * 4 + t] = cel[(size_t)(R0 + mb * 16 + lk * 4 + t) * FEAT + j];

        f32x4 acc[2][4];
        #pragma unroll
        for (int mb = 0; mb < 2; ++mb) {
            acc[mb][0] = (f32x4){bsf, bsf, bsf, bsf};
            acc[mb][1] = (f32x4){bsi, bsi, bsi, bsi};
            acc[mb][2] = (f32x4){bso, bso, bso, bso};
            acc[mb][3] = (f32x4){bsc, bsc, bsc, bsc};
        }

        #pragma unroll
        for (int kq = 0; kq < 4; ++kq) {
            // consume staged quarter
            bf16x8 afr[4];
            #pragma unroll
            for (int i = 0; i < 4; ++i) afr[i] = cvt8(slo[i], shi[i]);

            // stage next quarter (next iter's kq=0 when kq==3); pure register
            // dataflow -- these loads stay in flight under the MFMAs below.
            if (it < 3 || kq < 3) {
                const int kqn  = (kq + 1) & 3;
                const int R0n  = (kq == 3) ? R0 + 512 * 32 : R0;
                const float* S = (kqn < 2) ? inp : hid;
                const float* a = S + (size_t)(R0n + lr) * FEAT + (kqn & 1) * 64 + lk * 8;
                #pragma unroll
                for (int mb = 0; mb < 2; ++mb)
                    #pragma unroll
                    for (int c = 0; c < 2; ++c) {
                        slo[mb * 2 + c] = *(const f32x4*)(a + mb * 16 * FEAT + c * 32);
                        shi[mb * 2 + c] = *(const f32x4*)(a + mb * 16 * FEAT + c * 32 + 4);
                    }
            }

            // 16 MFMA: 2 k-steps x 4 gates x 2 m-blocks, W from L2 each time
            #pragma unroll
            for (int c = 0; c < 2; ++c) {
                const int ks = kq * 2 + c;
                #pragma unroll
                for (int g = 0; g < 4; ++g) {
                    const bf16x8 wf = wfb[(g * 8 + ks) * 64 + lane];
                    acc[0][g] = __builtin_amdgcn_mfma_f32_16x16x32_bf16(
                        afr[0 * 2 + c], wf, acc[0][g], 0, 0, 0);
                    acc[1][g] = __builtin_amdgcn_mfma_f32_16x16x32_bf16(
                        afr[1 * 2 + c], wf, acc[1][g], 0, 0, 0);
                }
            }
        }

        // lane-local LSTM epilogue: C/D col = lr, row = lk*4 + t (v1-proven)
        #pragma unroll
        for (int mb = 0; mb < 2; ++mb)
            #pragma unroll
            for (int t = 0; t < 4; ++t) {
                const size_t off = (size_t)(R0 + mb * 16 + lk * 4 + t) * FEAT + j;
                float fg = sigmoidf_(acc[mb][0][t]);
                float ig = sigmoidf_(acc[mb][1][t]);
                float og = sigmoidf_(acc[mb][2][t]);
                float gg = tanhf_(acc[mb][3][t]);
                float nc = fg * cv[mb * 4 + t] + ig * gg;
                float nh = og * tanhf_(nc);
                outH[off] = nh;
                outC[off] = nc;
            }
    }
}

extern "C" void kernel_launch(void* const* d_in, const int* in_sizes, int n_in,
                              void* d_out, int out_size, void* d_ws, size_t ws_size,
                              hipStream_t stream) {
    const float* inp = (const float*)d_in[0];
    const float* hid = (const float*)d_in[1];
    const float* cel = (const float*)d_in[2];
    const float* Wf  = (const float*)d_in[3];
    const float* bf  = (const float*)d_in[4];
    const float* Wi  = (const float*)d_in[5];
    const float* bi  = (const float*)d_in[6];
    const float* Wo  = (const float*)d_in[7];
    const float* bo  = (const float*)d_in[8];
    const float* Wc  = (const float*)d_in[9];
    const float* bc  = (const float*)d_in[10];
    float* out = (float*)d_out;

    bf16x8* wsf = (bf16x8*)d_ws;   // needs 16384 * 16 B = 256 KB

    prep_w<<<dim3(64), dim3(256), 0, stream>>>(Wf, Wi, Wo, Wc, wsf);
    lstm_v6<<<dim3(512), dim3(512), 0, stream>>>(
        inp, hid, cel, bf, bi, bo, bc, wsf, out);
}